// Round 1
// baseline (446.231 us; speedup 1.0000x reference)
//
#include <hip/hip_runtime.h>
#include <hip/hip_bf16.h>

#define BB 4
#define CC 256
#define NN 4096
#define SS 3
#define C8 32
#define L2E 1.4426950408889634f

typedef __attribute__((ext_vector_type(8))) short short8;
typedef __attribute__((ext_vector_type(4))) float floatx4;

static __device__ inline unsigned pack_bf16(float a, float b) {
  union { __hip_bfloat16 h; unsigned short u; } ua, ub;
  ua.h = __float2bfloat16(a);
  ub.h = __float2bfloat16(b);
  return ((unsigned)ub.u << 16) | (unsigned)ua.u;
}

static __device__ inline float fast_exp2(float x) {
#if __has_builtin(__builtin_amdgcn_exp2f)
  return __builtin_amdgcn_exp2f(x);
#else
  return exp2f(x);
#endif
}

// ---------------------------------------------------------------------------
// P0: prep = weight fp32->bf16 convert only (832 blocks). outs zeroing gone:
// attn now writes per-s partial slabs with plain stores (full overwrite).
// ---------------------------------------------------------------------------
__global__ void __launch_bounds__(256) prep_kernel(
    const float* __restrict__ Wq, const float* __restrict__ Wk,
    const float* __restrict__ Wv, const float* __restrict__ Wf,
    __hip_bfloat16* __restrict__ WqB, __hip_bfloat16* __restrict__ WkB,
    __hip_bfloat16* __restrict__ WvB, __hip_bfloat16* __restrict__ WfB) {
  int idx = blockIdx.x * 256 + threadIdx.x;
  if (idx < 8192) WqB[idx] = __float2bfloat16(Wq[idx] * L2E);
  else if (idx < 16384) WkB[idx - 8192] = __float2bfloat16(Wk[idx - 8192]);
  else if (idx < 81920) WvB[idx - 16384] = __float2bfloat16(Wv[idx - 16384]);
  else if (idx < 212992) WfB[idx - 81920] = __float2bfloat16(Wf[idx - 81920]);
}

// ---------------------------------------------------------------------------
// T1: input transposes, merged. z<12: xbT[z] <- x_b[z]; else xfT[z-12] <- x_f.
// ---------------------------------------------------------------------------
__global__ void __launch_bounds__(256) transpose_in_kernel(
    const float* __restrict__ xb, const float* __restrict__ xf,
    __hip_bfloat16* __restrict__ xbT, __hip_bfloat16* __restrict__ xfT) {
  __shared__ float ts[64][65];
  const int z = blockIdx.z;
  const bool isb = (z < 12);
  const int g = isb ? z : z - 12;
  const float* X = (isb ? xb : xf) + (size_t)g * CC * NN;
  __hip_bfloat16* out = (isb ? xbT : xfT) + (size_t)g * NN * CC;
  const int c0 = blockIdx.y * 64, n0 = blockIdx.x * 64;
  const int t = threadIdx.x;
  const float* Xg = X + (size_t)c0 * NN + n0;
  for (int idx = t; idx < 64 * 64; idx += 256) {
    int r = idx >> 6, qq = idx & 63;
    ts[r][qq] = Xg[(size_t)r * NN + qq];
  }
  __syncthreads();
  __hip_bfloat16* og = out + (size_t)n0 * CC + c0;
  for (int idx = t; idx < 64 * 32; idx += 256) {
    int n = idx >> 5, pc = idx & 31;
    ((unsigned*)(og + (size_t)n * CC))[pc] = pack_bf16(ts[2 * pc][n], ts[2 * pc + 1][n]);
  }
}

// ---------------------------------------------------------------------------
// T2: outsT2[b][n][c] = bf16( gamma * (outs_s[b] + outs_s[4+b] + outs_s[8+b]) )
// Fuses the 3-way s-sum (was atomicAdd in attn) into the transpose pass.
// ---------------------------------------------------------------------------
__global__ void __launch_bounds__(256) transpose_gamma_kernel(
    const float* __restrict__ outs_s, __hip_bfloat16* __restrict__ outsT2,
    const float* __restrict__ gp) {
  __shared__ float ts[64][65];
  const int b = blockIdx.z, c0 = blockIdx.y * 64, n0 = blockIdx.x * 64;
  const int t = threadIdx.x;
  const float sc = gp[0];
  const float* X0 = outs_s + ((size_t)(0 + b) * CC + c0) * NN + n0;
  const float* X1 = outs_s + ((size_t)(4 + b) * CC + c0) * NN + n0;
  const float* X2 = outs_s + ((size_t)(8 + b) * CC + c0) * NN + n0;
  for (int idx = t; idx < 64 * 64; idx += 256) {
    int r = idx >> 6, qq = idx & 63;
    size_t off = (size_t)r * NN + qq;
    ts[r][qq] = X0[off] + X1[off] + X2[off];
  }
  __syncthreads();
  __hip_bfloat16* og = outsT2 + (size_t)b * NN * CC + (size_t)n0 * CC + c0;
  for (int idx = t; idx < 64 * 32; idx += 256) {
    int n = idx >> 5, pc = idx & 31;
    ((unsigned*)(og + (size_t)n * CC))[pc] =
        pack_bf16(ts[2 * pc][n] * sc, ts[2 * pc + 1][n] * sc);
  }
}

// ---------------------------------------------------------------------------
// G1: q/k projection, MFMA.
// ---------------------------------------------------------------------------
__global__ void __launch_bounds__(256) projqk_kernel(
    const __hip_bfloat16* __restrict__ xbT, const __hip_bfloat16* __restrict__ xfT,
    const __hip_bfloat16* __restrict__ WqB, const __hip_bfloat16* __restrict__ WkB,
    const float* __restrict__ bq, const float* __restrict__ bk,
    __hip_bfloat16* __restrict__ qT, __hip_bfloat16* __restrict__ kT) {
  const int gg = blockIdx.y;
  const bool qm = (gg < 12);
  const int g = qm ? gg : gg - 12;
  const __hip_bfloat16* src = (qm ? xbT : xfT) + (size_t)g * NN * CC;
  const __hip_bfloat16* W = qm ? WqB : WkB;
  const float* bias = qm ? bq : bk;
  const float bscale = qm ? L2E : 1.f;
  __hip_bfloat16* dst = (qm ? qT : kT) + (size_t)g * NN * C8;
  const int t = threadIdx.x, w = t >> 6, lane = t & 63;
  const int q = lane >> 4, li = lane & 15;
  const int n_w = blockIdx.x * 256 + w * 64;
  floatx4 acc[2][4];
  floatx4 zf = {0.f, 0.f, 0.f, 0.f};
#pragma unroll
  for (int ot = 0; ot < 2; ++ot)
#pragma unroll
    for (int nt = 0; nt < 4; ++nt) acc[ot][nt] = zf;
#pragma unroll
  for (int kc = 0; kc < 8; ++kc) {
    short8 a[2], bfr[4];
#pragma unroll
    for (int ot = 0; ot < 2; ++ot)
      a[ot] = *(const short8*)(W + (size_t)(ot * 16 + li) * CC + kc * 32 + q * 8);
#pragma unroll
    for (int nt = 0; nt < 4; ++nt)
      bfr[nt] = *(const short8*)(src + (size_t)(n_w + nt * 16 + li) * CC + kc * 32 + q * 8);
#pragma unroll
    for (int ot = 0; ot < 2; ++ot)
#pragma unroll
      for (int nt = 0; nt < 4; ++nt)
        acc[ot][nt] = __builtin_amdgcn_mfma_f32_16x16x32_bf16(a[ot], bfr[nt],
                                                              acc[ot][nt], 0, 0, 0);
  }
#pragma unroll
  for (int ot = 0; ot < 2; ++ot) {
    float bv0 = bias[ot * 16 + q * 4 + 0] * bscale;
    float bv1 = bias[ot * 16 + q * 4 + 1] * bscale;
    float bv2 = bias[ot * 16 + q * 4 + 2] * bscale;
    float bv3 = bias[ot * 16 + q * 4 + 3] * bscale;
#pragma unroll
    for (int nt = 0; nt < 4; ++nt) {
      int n = n_w + nt * 16 + li;
      uint2 pk;
      pk.x = pack_bf16(acc[ot][nt][0] + bv0, acc[ot][nt][1] + bv1);
      pk.y = pack_bf16(acc[ot][nt][2] + bv2, acc[ot][nt][3] + bv3);
      *(uint2*)(dst + (size_t)n * C8 + ot * 16 + q * 4) = pk;
    }
  }
}

// ---------------------------------------------------------------------------
// G2: v projection, MFMA.
// ---------------------------------------------------------------------------
__global__ void __launch_bounds__(256) projv_kernel(
    const __hip_bfloat16* __restrict__ xbT, const __hip_bfloat16* __restrict__ WvB,
    const float* __restrict__ bv, __hip_bfloat16* __restrict__ vB) {
  const int g = blockIdx.y, n0 = blockIdx.x * 64;
  const int t = threadIdx.x, w = t >> 6, lane = t & 63;
  const int q = lane >> 4, li = lane & 15;
  const __hip_bfloat16* src = xbT + (size_t)g * NN * CC;
  __hip_bfloat16* dst = vB + (size_t)g * CC * NN;
  const int o_w = w * 64;
  floatx4 acc[4][4];
  floatx4 zf = {0.f, 0.f, 0.f, 0.f};
#pragma unroll
  for (int ot = 0; ot < 4; ++ot)
#pragma unroll
    for (int nt = 0; nt < 4; ++nt) acc[ot][nt] = zf;
#pragma unroll
  for (int kc = 0; kc < 8; ++kc) {
    short8 a[4], bfr[4];
#pragma unroll
    for (int ot = 0; ot < 4; ++ot)
      a[ot] = *(const short8*)(WvB + (size_t)(o_w + ot * 16 + li) * CC + kc * 32 + q * 8);
#pragma unroll
    for (int nt = 0; nt < 4; ++nt)
      bfr[nt] = *(const short8*)(src + (size_t)(n0 + nt * 16 + li) * CC + kc * 32 + q * 8);
#pragma unroll
    for (int ot = 0; ot < 4; ++ot)
#pragma unroll
      for (int nt = 0; nt < 4; ++nt)
        acc[ot][nt] = __builtin_amdgcn_mfma_f32_16x16x32_bf16(a[ot], bfr[nt],
                                                              acc[ot][nt], 0, 0, 0);
  }
#pragma unroll
  for (int ot = 0; ot < 4; ++ot) {
#pragma unroll
    for (int r = 0; r < 4; ++r) {
      int o = o_w + ot * 16 + q * 4 + r;
      float bo = bv[o];
#pragma unroll
      for (int nt = 0; nt < 4; ++nt)
        dst[(size_t)o * NN + n0 + nt * 16 + li] =
            __float2bfloat16(acc[ot][nt][r] + bo);
    }
  }
}

// ---------------------------------------------------------------------------
// K3: MFMA flash attention. 128-j outer iteration, 4 P-buffers, ONE barrier
// per 128 j (was 64 barriers -> 32). setprio(1) around PV MFMA clusters.
// Plain stores to per-s fp32 partial slabs outs_s[g] (no atomics, no zeroing).
// XCD-aware mapping kept: each XCD works a contiguous 96-block range ->
// V working set 3MB < 4MB L2.
// ---------------------------------------------------------------------------
__global__ void __launch_bounds__(256, 3) attn_kernel(
    const __hip_bfloat16* __restrict__ qT, const __hip_bfloat16* __restrict__ kT,
    const __hip_bfloat16* __restrict__ vB, float* __restrict__ outs_s) {
  __shared__ uint4 Ps4[4 * 64 * 8];  // 4 x 8KB P buffers, 16B-chunk XOR swizzle
  __shared__ float lsum[64];
  char* Ps0 = (char*)Ps4;
  const int x_ = blockIdx.x;
  const int wk = (x_ & 7) * 96 + (x_ >> 3);  // contiguous range per XCD
  const int g  = wk >> 6;                    // 0..11 (= s*4+b)
  const int i0 = (wk & 63) << 6;
  const int b  = g & 3;
  const int t  = threadIdx.x;
  const int w  = t >> 6;
  const int lane = t & 63, q = lane >> 4, li = lane & 15;

  if (t < 64) lsum[t] = 0.f;

  short8 qf[4];
#pragma unroll
  for (int it = 0; it < 4; ++it)
    qf[it] = *(const short8*)(qT + ((size_t)g * NN + i0 + it * 16 + li) * C8 + q * 8);

  floatx4 acc[4][4];
  floatx4 zf = {0.f, 0.f, 0.f, 0.f};
#pragma unroll
  for (int ct = 0; ct < 4; ++ct)
#pragma unroll
    for (int it = 0; it < 4; ++it) acc[ct][it] = zf;
  float rsum[4] = {0.f, 0.f, 0.f, 0.f};

  const __hip_bfloat16* kb = kT + (size_t)b * NN * C8;
  const __hip_bfloat16* vb = vB + (size_t)g * CC * NN;
  short8 kf0 = *(const short8*)(kb + (size_t)(0 + w * 16 + li) * C8 + q * 8);
  short8 kf1 = *(const short8*)(kb + (size_t)(64 + w * 16 + li) * C8 + q * 8);

  for (int j0 = 0; j0 < NN; j0 += 128) {
    // V frags for subtile A: issue first so L2 latency hides under S/exp work
    short8 vfA[4][2];
#pragma unroll
    for (int ct = 0; ct < 4; ++ct)
#pragma unroll
      for (int kk = 0; kk < 2; ++kk)
        vfA[ct][kk] = *(const short8*)(vb + (size_t)(w * 64 + ct * 16 + li) * NN +
                                       j0 + kk * 32 + q * 8);
    // S^T strips for both subtiles
    floatx4 stA[4], stB[4];
#pragma unroll
    for (int it = 0; it < 4; ++it)
      stA[it] = __builtin_amdgcn_mfma_f32_16x16x32_bf16(kf0, qf[it], zf, 0, 0, 0);
#pragma unroll
    for (int it = 0; it < 4; ++it)
      stB[it] = __builtin_amdgcn_mfma_f32_16x16x32_bf16(kf1, qf[it], zf, 0, 0, 0);
    // prefetch next iter's K frags (wrap harmless)
    int j0n = (j0 + 128) & (NN - 1);
    kf0 = *(const short8*)(kb + (size_t)(j0n + w * 16 + li) * C8 + q * 8);
    kf1 = *(const short8*)(kb + (size_t)(j0n + 64 + w * 16 + li) * C8 + q * 8);

    char* PsA = Ps0 + ((j0 >> 6) & 2) * 8192;  // pair {0,1} / {2,3} alternates
    char* PsB = PsA + 8192;
    // exp2 + row-sum partials + pack + LDS write, subtile A
    {
      uint2 pk[4];
#pragma unroll
      for (int it = 0; it < 4; ++it) {
        float e0 = fast_exp2(stA[it][0]), e1 = fast_exp2(stA[it][1]);
        float e2 = fast_exp2(stA[it][2]), e3 = fast_exp2(stA[it][3]);
        rsum[it] += (e0 + e1) + (e2 + e3);
        pk[it].x = pack_bf16(e0, e1);
        pk[it].y = pack_bf16(e2, e3);
      }
#pragma unroll
      for (int it = 0; it < 4; ++it) {
        int row = it * 16 + li;
        int chunk = (w * 2 + (q >> 1)) ^ (row & 7);
        *(uint2*)(PsA + row * 128 + chunk * 16 + (q & 1) * 8) = pk[it];
      }
    }
    // subtile B
    {
      uint2 pk[4];
#pragma unroll
      for (int it = 0; it < 4; ++it) {
        float e0 = fast_exp2(stB[it][0]), e1 = fast_exp2(stB[it][1]);
        float e2 = fast_exp2(stB[it][2]), e3 = fast_exp2(stB[it][3]);
        rsum[it] += (e0 + e1) + (e2 + e3);
        pk[it].x = pack_bf16(e0, e1);
        pk[it].y = pack_bf16(e2, e3);
      }
#pragma unroll
      for (int it = 0; it < 4; ++it) {
        int row = it * 16 + li;
        int chunk = (w * 2 + (q >> 1)) ^ (row & 7);
        *(uint2*)(PsB + row * 128 + chunk * 16 + (q & 1) * 8) = pk[it];
      }
    }
    __syncthreads();  // one barrier per 128 j; pair double-buffer makes reads safe
    // PV subtile A
    __builtin_amdgcn_s_setprio(1);
#pragma unroll
    for (int kk = 0; kk < 2; ++kk) {
      short8 pf[4];
#pragma unroll
      for (int it = 0; it < 4; ++it) {
        int row = it * 16 + li;
        int chunk = (kk * 4 + q) ^ (row & 7);
        pf[it] = *(const short8*)(PsA + row * 128 + chunk * 16);
      }
#pragma unroll
      for (int ct = 0; ct < 4; ++ct)
#pragma unroll
        for (int it = 0; it < 4; ++it)
          acc[ct][it] = __builtin_amdgcn_mfma_f32_16x16x32_bf16(
              vfA[ct][kk], pf[it], acc[ct][it], 0, 0, 0);
    }
    __builtin_amdgcn_s_setprio(0);
    // V frags for subtile B (vfA dead -> regs reuse; latency hides under pf reads)
    short8 vfB[4][2];
#pragma unroll
    for (int ct = 0; ct < 4; ++ct)
#pragma unroll
      for (int kk = 0; kk < 2; ++kk)
        vfB[ct][kk] = *(const short8*)(vb + (size_t)(w * 64 + ct * 16 + li) * NN +
                                       j0 + 64 + kk * 32 + q * 8);
    __builtin_amdgcn_s_setprio(1);
#pragma unroll
    for (int kk = 0; kk < 2; ++kk) {
      short8 pf[4];
#pragma unroll
      for (int it = 0; it < 4; ++it) {
        int row = it * 16 + li;
        int chunk = (kk * 4 + q) ^ (row & 7);
        pf[it] = *(const short8*)(PsB + row * 128 + chunk * 16);
      }
#pragma unroll
      for (int ct = 0; ct < 4; ++ct)
#pragma unroll
        for (int it = 0; it < 4; ++it)
          acc[ct][it] = __builtin_amdgcn_mfma_f32_16x16x32_bf16(
              vfB[ct][kk], pf[it], acc[ct][it], 0, 0, 0);
    }
    __builtin_amdgcn_s_setprio(0);
  }
#pragma unroll
  for (int it = 0; it < 4; ++it) {
    float v = rsum[it];
    v += __shfl_xor(v, 16, 64);
    v += __shfl_xor(v, 32, 64);
    if (lane < 16) atomicAdd(&lsum[it * 16 + li], v);
  }
  __syncthreads();
  float inv[4];
#pragma unroll
  for (int it = 0; it < 4; ++it) inv[it] = 1.0f / lsum[it * 16 + li];
  float* ob = outs_s + (size_t)g * CC * NN + i0;
#pragma unroll
  for (int ct = 0; ct < 4; ++ct)
#pragma unroll
    for (int it = 0; it < 4; ++it)
#pragma unroll
      for (int r = 0; r < 4; ++r) {
        int c = w * 64 + ct * 16 + q * 4 + r;
        ob[(size_t)c * NN + it * 16 + li] = acc[ct][it][r] * inv[it];
      }
}

// ---------------------------------------------------------------------------
// G3: final projection, MFMA.
// ---------------------------------------------------------------------------
__global__ void __launch_bounds__(256) final_kernel(
    const __hip_bfloat16* __restrict__ outsT2, const __hip_bfloat16* __restrict__ xfT,
    const __hip_bfloat16* __restrict__ WfB, const float* __restrict__ bfv,
    float* __restrict__ out) {
  const int b = blockIdx.y, n0 = blockIdx.x * 64;
  const int t = threadIdx.x, w = t >> 6, lane = t & 63;
  const int q = lane >> 4, li = lane & 15;
  const int o_w = w * 64;
  const __hip_bfloat16* oT = outsT2 + (size_t)b * NN * CC;
  const __hip_bfloat16* xT = xfT + (size_t)b * NN * CC;
  floatx4 acc[4][4];
  floatx4 zf = {0.f, 0.f, 0.f, 0.f};
#pragma unroll
  for (int ot = 0; ot < 4; ++ot)
#pragma unroll
    for (int nt = 0; nt < 4; ++nt) acc[ot][nt] = zf;
#pragma unroll
  for (int kc = 0; kc < 16; ++kc) {
    const __hip_bfloat16* src = (kc < 8) ? oT : xT;
    int kb = (kc & 7) * 32;
    short8 a[4], bfr[4];
#pragma unroll
    for (int ot = 0; ot < 4; ++ot)
      a[ot] = *(const short8*)(WfB + (size_t)(o_w + ot * 16 + li) * (2 * CC) +
                               kc * 32 + q * 8);
#pragma unroll
    for (int nt = 0; nt < 4; ++nt)
      bfr[nt] = *(const short8*)(src + (size_t)(n0 + nt * 16 + li) * CC + kb + q * 8);
#pragma unroll
    for (int ot = 0; ot < 4; ++ot)
#pragma unroll
      for (int nt = 0; nt < 4; ++nt)
        acc[ot][nt] = __builtin_amdgcn_mfma_f32_16x16x32_bf16(a[ot], bfr[nt],
                                                              acc[ot][nt], 0, 0, 0);
  }
  float* ob = out + (size_t)b * CC * NN;
#pragma unroll
  for (int ot = 0; ot < 4; ++ot)
#pragma unroll
    for (int r = 0; r < 4; ++r) {
      int o = o_w + ot * 16 + q * 4 + r;
      float bo = bfv[o];
#pragma unroll
      for (int nt = 0; nt < 4; ++nt)
        ob[(size_t)o * NN + n0 + nt * 16 + li] = acc[ot][nt][r] + bo;
    }
}

// ---------------------------------------------------------------------------
extern "C" void kernel_launch(void* const* d_in, const int* in_sizes, int n_in,
                              void* d_out, int out_size, void* d_ws,
                              size_t ws_size, hipStream_t stream) {
  const float* x_f = (const float*)d_in[0];
  const float* x_b = (const float*)d_in[1];
  const float* Wq  = (const float*)d_in[2];
  const float* bq  = (const float*)d_in[3];
  const float* Wk  = (const float*)d_in[4];
  const float* bk  = (const float*)d_in[5];
  const float* Wv  = (const float*)d_in[6];
  const float* bv  = (const float*)d_in[7];
  const float* Wf  = (const float*)d_in[8];
  const float* bf  = (const float*)d_in[9];
  const float* gm  = (const float*)d_in[10];
  float* out = (float*)d_out;

  // workspace layout — peak 84.4 MB (same as previous version), via aliasing:
  //   [ 0..24) vB       bf16 [12][256][4096]   (projv -> attn)
  //            outsT2   bf16 [4][4096][256]    (tg -> final)  ALIAS: vB dead
  //   [24..32) xfT      bf16 [4][4096][256]    (transpose -> final)
  //   [32..80) outs_s   f32  [12][256][4096]   (attn -> tg)
  //            xbT      bf16 [12][4096][256]   (transpose -> projv) ALIAS:
  //                                            xbT dead before attn writes
  //   [80..83) qT, [83..84) kT, [84..84.41) weights
  char* ws = (char*)d_ws;
  __hip_bfloat16* vB     = (__hip_bfloat16*)ws;                         // 24 MB
  __hip_bfloat16* outsT2 = (__hip_bfloat16*)ws;                         //  8 MB (alias vB)
  __hip_bfloat16* xfT    = (__hip_bfloat16*)(ws + ((size_t)24 << 20));  //  8 MB
  float*          outs_s = (float*)(ws + ((size_t)32 << 20));           // 48 MB
  __hip_bfloat16* xbT    = (__hip_bfloat16*)(ws + ((size_t)32 << 20));  // 24 MB (alias outs_s)
  __hip_bfloat16* qT     = (__hip_bfloat16*)(ws + ((size_t)80 << 20));  //  3 MB
  __hip_bfloat16* kT     = (__hip_bfloat16*)(ws + ((size_t)83 << 20));  //  1 MB
  __hip_bfloat16* WqB    = (__hip_bfloat16*)(ws + ((size_t)84 << 20));  // 16 KB
  __hip_bfloat16* WkB    = WqB + 8192;                                  // 16 KB
  __hip_bfloat16* WvB    = WkB + 8192;                                  // 128 KB
  __hip_bfloat16* WfB    = WvB + 65536;                                 // 256 KB

  hipLaunchKernelGGL(prep_kernel, dim3(832), dim3(256), 0, stream,
                     Wq, Wk, Wv, Wf, WqB, WkB, WvB, WfB);
  hipLaunchKernelGGL(transpose_in_kernel, dim3(NN / 64, CC / 64, 16),
                     dim3(256), 0, stream, x_b, x_f, xbT, xfT);
  hipLaunchKernelGGL(projqk_kernel, dim3(NN / 256, 16), dim3(256), 0, stream,
                     xbT, xfT, WqB, WkB, bq, bk, qT, kT);
  hipLaunchKernelGGL(projv_kernel, dim3(NN / 64, SS * BB), dim3(256), 0,
                     stream, xbT, WvB, bv, vB);
  hipLaunchKernelGGL(attn_kernel, dim3(768), dim3(256), 0, stream,
                     qT, kT, vB, outs_s);
  hipLaunchKernelGGL(transpose_gamma_kernel, dim3(NN / 64, CC / 64, BB),
                     dim3(256), 0, stream, outs_s, outsT2, gm);
  hipLaunchKernelGGL(final_kernel, dim3(NN / 64, BB), dim3(256), 0, stream,
                     outsT2, xfT, WfB, bf, out);
}

// Round 2
// 383.012 us; speedup vs baseline: 1.1651x; 1.1651x over previous
//
#include <hip/hip_runtime.h>
#include <hip/hip_bf16.h>

#define BB 4
#define CC 256
#define NN 4096
#define SS 3
#define C8 32
#define L2E 1.4426950408889634f

typedef __attribute__((ext_vector_type(8))) short short8;
typedef __attribute__((ext_vector_type(4))) float floatx4;

static __device__ inline unsigned pack_bf16(float a, float b) {
  union { __hip_bfloat16 h; unsigned short u; } ua, ub;
  ua.h = __float2bfloat16(a);
  ub.h = __float2bfloat16(b);
  return ((unsigned)ub.u << 16) | (unsigned)ua.u;
}

static __device__ inline float fast_exp2(float x) {
#if __has_builtin(__builtin_amdgcn_exp2f)
  return __builtin_amdgcn_exp2f(x);
#else
  return exp2f(x);
#endif
}

// ---------------------------------------------------------------------------
// P0: prep = weight fp32->bf16 convert only (832 blocks).
// ---------------------------------------------------------------------------
__global__ void __launch_bounds__(256) prep_kernel(
    const float* __restrict__ Wq, const float* __restrict__ Wk,
    const float* __restrict__ Wv, const float* __restrict__ Wf,
    __hip_bfloat16* __restrict__ WqB, __hip_bfloat16* __restrict__ WkB,
    __hip_bfloat16* __restrict__ WvB, __hip_bfloat16* __restrict__ WfB) {
  int idx = blockIdx.x * 256 + threadIdx.x;
  if (idx < 8192) WqB[idx] = __float2bfloat16(Wq[idx] * L2E);
  else if (idx < 16384) WkB[idx - 8192] = __float2bfloat16(Wk[idx - 8192]);
  else if (idx < 81920) WvB[idx - 16384] = __float2bfloat16(Wv[idx - 16384]);
  else if (idx < 212992) WfB[idx - 81920] = __float2bfloat16(Wf[idx - 81920]);
}

// ---------------------------------------------------------------------------
// T1: input transposes, merged. z<12: xbT[z] <- x_b[z]; else xfT[z-12] <- x_f.
// ---------------------------------------------------------------------------
__global__ void __launch_bounds__(256) transpose_in_kernel(
    const float* __restrict__ xb, const float* __restrict__ xf,
    __hip_bfloat16* __restrict__ xbT, __hip_bfloat16* __restrict__ xfT) {
  __shared__ float ts[64][65];
  const int z = blockIdx.z;
  const bool isb = (z < 12);
  const int g = isb ? z : z - 12;
  const float* X = (isb ? xb : xf) + (size_t)g * CC * NN;
  __hip_bfloat16* out = (isb ? xbT : xfT) + (size_t)g * NN * CC;
  const int c0 = blockIdx.y * 64, n0 = blockIdx.x * 64;
  const int t = threadIdx.x;
  const float* Xg = X + (size_t)c0 * NN + n0;
  for (int idx = t; idx < 64 * 64; idx += 256) {
    int r = idx >> 6, qq = idx & 63;
    ts[r][qq] = Xg[(size_t)r * NN + qq];
  }
  __syncthreads();
  __hip_bfloat16* og = out + (size_t)n0 * CC + c0;
  for (int idx = t; idx < 64 * 32; idx += 256) {
    int n = idx >> 5, pc = idx & 31;
    ((unsigned*)(og + (size_t)n * CC))[pc] = pack_bf16(ts[2 * pc][n], ts[2 * pc + 1][n]);
  }
}

// ---------------------------------------------------------------------------
// T2: outsT2[b][n][c] = bf16( gamma * (outs_s[b] + outs_s[4+b] + outs_s[8+b]) )
// ---------------------------------------------------------------------------
__global__ void __launch_bounds__(256) transpose_gamma_kernel(
    const float* __restrict__ outs_s, __hip_bfloat16* __restrict__ outsT2,
    const float* __restrict__ gp) {
  __shared__ float ts[64][65];
  const int b = blockIdx.z, c0 = blockIdx.y * 64, n0 = blockIdx.x * 64;
  const int t = threadIdx.x;
  const float sc = gp[0];
  const float* X0 = outs_s + ((size_t)(0 + b) * CC + c0) * NN + n0;
  const float* X1 = outs_s + ((size_t)(4 + b) * CC + c0) * NN + n0;
  const float* X2 = outs_s + ((size_t)(8 + b) * CC + c0) * NN + n0;
  for (int idx = t; idx < 64 * 64; idx += 256) {
    int r = idx >> 6, qq = idx & 63;
    size_t off = (size_t)r * NN + qq;
    ts[r][qq] = X0[off] + X1[off] + X2[off];
  }
  __syncthreads();
  __hip_bfloat16* og = outsT2 + (size_t)b * NN * CC + (size_t)n0 * CC + c0;
  for (int idx = t; idx < 64 * 32; idx += 256) {
    int n = idx >> 5, pc = idx & 31;
    ((unsigned*)(og + (size_t)n * CC))[pc] =
        pack_bf16(ts[2 * pc][n] * sc, ts[2 * pc + 1][n] * sc);
  }
}

// ---------------------------------------------------------------------------
// G1: q/k projection, MFMA.
// ---------------------------------------------------------------------------
__global__ void __launch_bounds__(256) projqk_kernel(
    const __hip_bfloat16* __restrict__ xbT, const __hip_bfloat16* __restrict__ xfT,
    const __hip_bfloat16* __restrict__ WqB, const __hip_bfloat16* __restrict__ WkB,
    const float* __restrict__ bq, const float* __restrict__ bk,
    __hip_bfloat16* __restrict__ qT, __hip_bfloat16* __restrict__ kT) {
  const int gg = blockIdx.y;
  const bool qm = (gg < 12);
  const int g = qm ? gg : gg - 12;
  const __hip_bfloat16* src = (qm ? xbT : xfT) + (size_t)g * NN * CC;
  const __hip_bfloat16* W = qm ? WqB : WkB;
  const float* bias = qm ? bq : bk;
  const float bscale = qm ? L2E : 1.f;
  __hip_bfloat16* dst = (qm ? qT : kT) + (size_t)g * NN * C8;
  const int t = threadIdx.x, w = t >> 6, lane = t & 63;
  const int q = lane >> 4, li = lane & 15;
  const int n_w = blockIdx.x * 256 + w * 64;
  floatx4 acc[2][4];
  floatx4 zf = {0.f, 0.f, 0.f, 0.f};
#pragma unroll
  for (int ot = 0; ot < 2; ++ot)
#pragma unroll
    for (int nt = 0; nt < 4; ++nt) acc[ot][nt] = zf;
#pragma unroll
  for (int kc = 0; kc < 8; ++kc) {
    short8 a[2], bfr[4];
#pragma unroll
    for (int ot = 0; ot < 2; ++ot)
      a[ot] = *(const short8*)(W + (size_t)(ot * 16 + li) * CC + kc * 32 + q * 8);
#pragma unroll
    for (int nt = 0; nt < 4; ++nt)
      bfr[nt] = *(const short8*)(src + (size_t)(n_w + nt * 16 + li) * CC + kc * 32 + q * 8);
#pragma unroll
    for (int ot = 0; ot < 2; ++ot)
#pragma unroll
      for (int nt = 0; nt < 4; ++nt)
        acc[ot][nt] = __builtin_amdgcn_mfma_f32_16x16x32_bf16(a[ot], bfr[nt],
                                                              acc[ot][nt], 0, 0, 0);
  }
#pragma unroll
  for (int ot = 0; ot < 2; ++ot) {
    float bv0 = bias[ot * 16 + q * 4 + 0] * bscale;
    float bv1 = bias[ot * 16 + q * 4 + 1] * bscale;
    float bv2 = bias[ot * 16 + q * 4 + 2] * bscale;
    float bv3 = bias[ot * 16 + q * 4 + 3] * bscale;
#pragma unroll
    for (int nt = 0; nt < 4; ++nt) {
      int n = n_w + nt * 16 + li;
      uint2 pk;
      pk.x = pack_bf16(acc[ot][nt][0] + bv0, acc[ot][nt][1] + bv1);
      pk.y = pack_bf16(acc[ot][nt][2] + bv2, acc[ot][nt][3] + bv3);
      *(uint2*)(dst + (size_t)n * C8 + ot * 16 + q * 4) = pk;
    }
  }
}

// ---------------------------------------------------------------------------
// G2: v projection, MFMA.
// ---------------------------------------------------------------------------
__global__ void __launch_bounds__(256) projv_kernel(
    const __hip_bfloat16* __restrict__ xbT, const __hip_bfloat16* __restrict__ WvB,
    const float* __restrict__ bv, __hip_bfloat16* __restrict__ vB) {
  const int g = blockIdx.y, n0 = blockIdx.x * 64;
  const int t = threadIdx.x, w = t >> 6, lane = t & 63;
  const int q = lane >> 4, li = lane & 15;
  const __hip_bfloat16* src = xbT + (size_t)g * NN * CC;
  __hip_bfloat16* dst = vB + (size_t)g * CC * NN;
  const int o_w = w * 64;
  floatx4 acc[4][4];
  floatx4 zf = {0.f, 0.f, 0.f, 0.f};
#pragma unroll
  for (int ot = 0; ot < 4; ++ot)
#pragma unroll
    for (int nt = 0; nt < 4; ++nt) acc[ot][nt] = zf;
#pragma unroll
  for (int kc = 0; kc < 8; ++kc) {
    short8 a[4], bfr[4];
#pragma unroll
    for (int ot = 0; ot < 4; ++ot)
      a[ot] = *(const short8*)(WvB + (size_t)(o_w + ot * 16 + li) * CC + kc * 32 + q * 8);
#pragma unroll
    for (int nt = 0; nt < 4; ++nt)
      bfr[nt] = *(const short8*)(src + (size_t)(n0 + nt * 16 + li) * CC + kc * 32 + q * 8);
#pragma unroll
    for (int ot = 0; ot < 4; ++ot)
#pragma unroll
      for (int nt = 0; nt < 4; ++nt)
        acc[ot][nt] = __builtin_amdgcn_mfma_f32_16x16x32_bf16(a[ot], bfr[nt],
                                                              acc[ot][nt], 0, 0, 0);
  }
#pragma unroll
  for (int ot = 0; ot < 4; ++ot) {
#pragma unroll
    for (int r = 0; r < 4; ++r) {
      int o = o_w + ot * 16 + q * 4 + r;
      float bo = bv[o];
#pragma unroll
      for (int nt = 0; nt < 4; ++nt)
        dst[(size_t)o * NN + n0 + nt * 16 + li] =
            __float2bfloat16(acc[ot][nt][r] + bo);
    }
  }
}

// ---------------------------------------------------------------------------
// K3: MFMA flash attention. 128-j outer iteration, 4 P-buffers, ONE barrier
// per 128 j. Register-lifetime serialized: stA dies into pack-A before stB is
// computed; vfB loaded only after PV-A kills vfA. Plain __launch_bounds__(256)
// — the (256,3) variant forced an 84-VGPR allocation (512/6 granule) and
// spilled to scratch (round-1: +9.5MB FETCH, +19MB WRITE, VALUBusy 40->15).
// Plain stores to per-s fp32 partial slabs outs_s[g] (no atomics, no zeroing).
// ---------------------------------------------------------------------------
__global__ void __launch_bounds__(256) attn_kernel(
    const __hip_bfloat16* __restrict__ qT, const __hip_bfloat16* __restrict__ kT,
    const __hip_bfloat16* __restrict__ vB, float* __restrict__ outs_s) {
  __shared__ uint4 Ps4[4 * 64 * 8];  // 4 x 8KB P buffers, 16B-chunk XOR swizzle
  __shared__ float lsum[64];
  char* Ps0 = (char*)Ps4;
  const int x_ = blockIdx.x;
  const int wk = (x_ & 7) * 96 + (x_ >> 3);  // contiguous range per XCD
  const int g  = wk >> 6;                    // 0..11 (= s*4+b)
  const int i0 = (wk & 63) << 6;
  const int b  = g & 3;
  const int t  = threadIdx.x;
  const int w  = t >> 6;
  const int lane = t & 63, q = lane >> 4, li = lane & 15;

  if (t < 64) lsum[t] = 0.f;

  short8 qf[4];
#pragma unroll
  for (int it = 0; it < 4; ++it)
    qf[it] = *(const short8*)(qT + ((size_t)g * NN + i0 + it * 16 + li) * C8 + q * 8);

  floatx4 acc[4][4];
  floatx4 zf = {0.f, 0.f, 0.f, 0.f};
#pragma unroll
  for (int ct = 0; ct < 4; ++ct)
#pragma unroll
    for (int it = 0; it < 4; ++it) acc[ct][it] = zf;
  float rsum[4] = {0.f, 0.f, 0.f, 0.f};

  const __hip_bfloat16* kb = kT + (size_t)b * NN * C8;
  const __hip_bfloat16* vb = vB + (size_t)g * CC * NN;
  short8 kf0 = *(const short8*)(kb + (size_t)(0 + w * 16 + li) * C8 + q * 8);
  short8 kf1 = *(const short8*)(kb + (size_t)(64 + w * 16 + li) * C8 + q * 8);

  for (int j0 = 0; j0 < NN; j0 += 128) {
    int j0n = (j0 + 128) & (NN - 1);
    char* PsA = Ps0 + ((j0 >> 6) & 2) * 8192;  // pair {0,1} / {2,3} alternates
    char* PsB = PsA + 8192;
    // V frags for subtile A: issue first so L2 latency hides under S/exp work
    short8 vfA[4][2];
#pragma unroll
    for (int ct = 0; ct < 4; ++ct)
#pragma unroll
      for (int kk = 0; kk < 2; ++kk)
        vfA[ct][kk] = *(const short8*)(vb + (size_t)(w * 64 + ct * 16 + li) * NN +
                                       j0 + kk * 32 + q * 8);
    // --- subtile A: S^T strip, exp2, pack, LDS write (stA dies here) ---
    {
      floatx4 stA[4];
#pragma unroll
      for (int it = 0; it < 4; ++it)
        stA[it] = __builtin_amdgcn_mfma_f32_16x16x32_bf16(kf0, qf[it], zf, 0, 0, 0);
      kf0 = *(const short8*)(kb + (size_t)(j0n + w * 16 + li) * C8 + q * 8);
      uint2 pk[4];
#pragma unroll
      for (int it = 0; it < 4; ++it) {
        float e0 = fast_exp2(stA[it][0]), e1 = fast_exp2(stA[it][1]);
        float e2 = fast_exp2(stA[it][2]), e3 = fast_exp2(stA[it][3]);
        rsum[it] += (e0 + e1) + (e2 + e3);
        pk[it].x = pack_bf16(e0, e1);
        pk[it].y = pack_bf16(e2, e3);
      }
#pragma unroll
      for (int it = 0; it < 4; ++it) {
        int row = it * 16 + li;
        int chunk = (w * 2 + (q >> 1)) ^ (row & 7);
        *(uint2*)(PsA + row * 128 + chunk * 16 + (q & 1) * 8) = pk[it];
      }
    }
    // --- subtile B: S^T strip, exp2, pack, LDS write ---
    {
      floatx4 stB[4];
#pragma unroll
      for (int it = 0; it < 4; ++it)
        stB[it] = __builtin_amdgcn_mfma_f32_16x16x32_bf16(kf1, qf[it], zf, 0, 0, 0);
      kf1 = *(const short8*)(kb + (size_t)(j0n + 64 + w * 16 + li) * C8 + q * 8);
      uint2 pk[4];
#pragma unroll
      for (int it = 0; it < 4; ++it) {
        float e0 = fast_exp2(stB[it][0]), e1 = fast_exp2(stB[it][1]);
        float e2 = fast_exp2(stB[it][2]), e3 = fast_exp2(stB[it][3]);
        rsum[it] += (e0 + e1) + (e2 + e3);
        pk[it].x = pack_bf16(e0, e1);
        pk[it].y = pack_bf16(e2, e3);
      }
#pragma unroll
      for (int it = 0; it < 4; ++it) {
        int row = it * 16 + li;
        int chunk = (w * 2 + (q >> 1)) ^ (row & 7);
        *(uint2*)(PsB + row * 128 + chunk * 16 + (q & 1) * 8) = pk[it];
      }
    }
    __syncthreads();  // one barrier per 128 j; alternating pairs make reads safe
    // --- PV subtile A (vfA dies here) ---
    __builtin_amdgcn_s_setprio(1);
#pragma unroll
    for (int kk = 0; kk < 2; ++kk) {
      short8 pf[4];
#pragma unroll
      for (int it = 0; it < 4; ++it) {
        int row = it * 16 + li;
        int chunk = (kk * 4 + q) ^ (row & 7);
        pf[it] = *(const short8*)(PsA + row * 128 + chunk * 16);
      }
#pragma unroll
      for (int ct = 0; ct < 4; ++ct)
#pragma unroll
        for (int it = 0; it < 4; ++it)
          acc[ct][it] = __builtin_amdgcn_mfma_f32_16x16x32_bf16(
              vfA[ct][kk], pf[it], acc[ct][it], 0, 0, 0);
    }
    __builtin_amdgcn_s_setprio(0);
    // V frags for subtile B (vfA dead -> regs reuse)
    short8 vfB[4][2];
#pragma unroll
    for (int ct = 0; ct < 4; ++ct)
#pragma unroll
      for (int kk = 0; kk < 2; ++kk)
        vfB[ct][kk] = *(const short8*)(vb + (size_t)(w * 64 + ct * 16 + li) * NN +
                                       j0 + 64 + kk * 32 + q * 8);
    // --- PV subtile B ---
    __builtin_amdgcn_s_setprio(1);
#pragma unroll
    for (int kk = 0; kk < 2; ++kk) {
      short8 pf[4];
#pragma unroll
      for (int it = 0; it < 4; ++it) {
        int row = it * 16 + li;
        int chunk = (kk * 4 + q) ^ (row & 7);
        pf[it] = *(const short8*)(PsB + row * 128 + chunk * 16);
      }
#pragma unroll
      for (int ct = 0; ct < 4; ++ct)
#pragma unroll
        for (int it = 0; it < 4; ++it)
          acc[ct][it] = __builtin_amdgcn_mfma_f32_16x16x32_bf16(
              vfB[ct][kk], pf[it], acc[ct][it], 0, 0, 0);
    }
    __builtin_amdgcn_s_setprio(0);
  }
#pragma unroll
  for (int it = 0; it < 4; ++it) {
    float v = rsum[it];
    v += __shfl_xor(v, 16, 64);
    v += __shfl_xor(v, 32, 64);
    if (lane < 16) atomicAdd(&lsum[it * 16 + li], v);
  }
  __syncthreads();
  float inv[4];
#pragma unroll
  for (int it = 0; it < 4; ++it) inv[it] = 1.0f / lsum[it * 16 + li];
  float* ob = outs_s + (size_t)g * CC * NN + i0;
#pragma unroll
  for (int ct = 0; ct < 4; ++ct)
#pragma unroll
    for (int it = 0; it < 4; ++it)
#pragma unroll
      for (int r = 0; r < 4; ++r) {
        int c = w * 64 + ct * 16 + q * 4 + r;
        ob[(size_t)c * NN + it * 16 + li] = acc[ct][it][r] * inv[it];
      }
}

// ---------------------------------------------------------------------------
// G3: final projection, MFMA.
// ---------------------------------------------------------------------------
__global__ void __launch_bounds__(256) final_kernel(
    const __hip_bfloat16* __restrict__ outsT2, const __hip_bfloat16* __restrict__ xfT,
    const __hip_bfloat16* __restrict__ WfB, const float* __restrict__ bfv,
    float* __restrict__ out) {
  const int b = blockIdx.y, n0 = blockIdx.x * 64;
  const int t = threadIdx.x, w = t >> 6, lane = t & 63;
  const int q = lane >> 4, li = lane & 15;
  const int o_w = w * 64;
  const __hip_bfloat16* oT = outsT2 + (size_t)b * NN * CC;
  const __hip_bfloat16* xT = xfT + (size_t)b * NN * CC;
  floatx4 acc[4][4];
  floatx4 zf = {0.f, 0.f, 0.f, 0.f};
#pragma unroll
  for (int ot = 0; ot < 4; ++ot)
#pragma unroll
    for (int nt = 0; nt < 4; ++nt) acc[ot][nt] = zf;
#pragma unroll
  for (int kc = 0; kc < 16; ++kc) {
    const __hip_bfloat16* src = (kc < 8) ? oT : xT;
    int kb = (kc & 7) * 32;
    short8 a[4], bfr[4];
#pragma unroll
    for (int ot = 0; ot < 4; ++ot)
      a[ot] = *(const short8*)(WfB + (size_t)(o_w + ot * 16 + li) * (2 * CC) +
                               kc * 32 + q * 8);
#pragma unroll
    for (int nt = 0; nt < 4; ++nt)
      bfr[nt] = *(const short8*)(src + (size_t)(n0 + nt * 16 + li) * CC + kb + q * 8);
#pragma unroll
    for (int ot = 0; ot < 4; ++ot)
#pragma unroll
      for (int nt = 0; nt < 4; ++nt)
        acc[ot][nt] = __builtin_amdgcn_mfma_f32_16x16x32_bf16(a[ot], bfr[nt],
                                                              acc[ot][nt], 0, 0, 0);
  }
  float* ob = out + (size_t)b * CC * NN;
#pragma unroll
  for (int ot = 0; ot < 4; ++ot)
#pragma unroll
    for (int r = 0; r < 4; ++r) {
      int o = o_w + ot * 16 + q * 4 + r;
      float bo = bfv[o];
#pragma unroll
      for (int nt = 0; nt < 4; ++nt)
        ob[(size_t)o * NN + n0 + nt * 16 + li] = acc[ot][nt][r] + bo;
    }
}

// ---------------------------------------------------------------------------
extern "C" void kernel_launch(void* const* d_in, const int* in_sizes, int n_in,
                              void* d_out, int out_size, void* d_ws,
                              size_t ws_size, hipStream_t stream) {
  const float* x_f = (const float*)d_in[0];
  const float* x_b = (const float*)d_in[1];
  const float* Wq  = (const float*)d_in[2];
  const float* bq  = (const float*)d_in[3];
  const float* Wk  = (const float*)d_in[4];
  const float* bk  = (const float*)d_in[5];
  const float* Wv  = (const float*)d_in[6];
  const float* bv  = (const float*)d_in[7];
  const float* Wf  = (const float*)d_in[8];
  const float* bf  = (const float*)d_in[9];
  const float* gm  = (const float*)d_in[10];
  float* out = (float*)d_out;

  // workspace layout — peak 84.4 MB via aliasing:
  //   [ 0..24) vB       bf16 [12][256][4096]   (projv -> attn)
  //            outsT2   bf16 [4][4096][256]    (tg -> final)  ALIAS: vB dead
  //   [24..32) xfT      bf16 [4][4096][256]    (transpose -> final)
  //   [32..80) outs_s   f32  [12][256][4096]   (attn -> tg)
  //            xbT      bf16 [12][4096][256]   (transpose -> projv) ALIAS
  //   [80..83) qT, [83..84) kT, [84..84.41) weights
  char* ws = (char*)d_ws;
  __hip_bfloat16* vB     = (__hip_bfloat16*)ws;                         // 24 MB
  __hip_bfloat16* outsT2 = (__hip_bfloat16*)ws;                         //  8 MB (alias vB)
  __hip_bfloat16* xfT    = (__hip_bfloat16*)(ws + ((size_t)24 << 20));  //  8 MB
  float*          outs_s = (float*)(ws + ((size_t)32 << 20));           // 48 MB
  __hip_bfloat16* xbT    = (__hip_bfloat16*)(ws + ((size_t)32 << 20));  // 24 MB (alias outs_s)
  __hip_bfloat16* qT     = (__hip_bfloat16*)(ws + ((size_t)80 << 20));  //  3 MB
  __hip_bfloat16* kT     = (__hip_bfloat16*)(ws + ((size_t)83 << 20));  //  1 MB
  __hip_bfloat16* WqB    = (__hip_bfloat16*)(ws + ((size_t)84 << 20));  // 16 KB
  __hip_bfloat16* WkB    = WqB + 8192;                                  // 16 KB
  __hip_bfloat16* WvB    = WkB + 8192;                                  // 128 KB
  __hip_bfloat16* WfB    = WvB + 65536;                                 // 256 KB

  hipLaunchKernelGGL(prep_kernel, dim3(832), dim3(256), 0, stream,
                     Wq, Wk, Wv, Wf, WqB, WkB, WvB, WfB);
  hipLaunchKernelGGL(transpose_in_kernel, dim3(NN / 64, CC / 64, 16),
                     dim3(256), 0, stream, x_b, x_f, xbT, xfT);
  hipLaunchKernelGGL(projqk_kernel, dim3(NN / 256, 16), dim3(256), 0, stream,
                     xbT, xfT, WqB, WkB, bq, bk, qT, kT);
  hipLaunchKernelGGL(projv_kernel, dim3(NN / 64, SS * BB), dim3(256), 0,
                     stream, xbT, WvB, bv, vB);
  hipLaunchKernelGGL(attn_kernel, dim3(768), dim3(256), 0, stream,
                     qT, kT, vB, outs_s);
  hipLaunchKernelGGL(transpose_gamma_kernel, dim3(NN / 64, CC / 64, BB),
                     dim3(256), 0, stream, outs_s, outsT2, gm);
  hipLaunchKernelGGL(final_kernel, dim3(NN / 64, BB), dim3(256), 0, stream,
                     outsT2, xfT, WfB, bf, out);
}

// Round 3
// 381.728 us; speedup vs baseline: 1.1690x; 1.0034x over previous
//
#include <hip/hip_runtime.h>
#include <hip/hip_bf16.h>

#define BB 4
#define CC 256
#define NN 4096
#define SS 3
#define C8 32
#define L2E 1.4426950408889634f

typedef __attribute__((ext_vector_type(8))) short short8;
typedef __attribute__((ext_vector_type(4))) float floatx4;

static __device__ inline unsigned pack_bf16(float a, float b) {
  union { __hip_bfloat16 h; unsigned short u; } ua, ub;
  ua.h = __float2bfloat16(a);
  ub.h = __float2bfloat16(b);
  return ((unsigned)ub.u << 16) | (unsigned)ua.u;
}

static __device__ inline float fast_exp2(float x) {
#if __has_builtin(__builtin_amdgcn_exp2f)
  return __builtin_amdgcn_exp2f(x);
#else
  return exp2f(x);
#endif
}

// ---------------------------------------------------------------------------
// P0: prep = weight fp32->bf16 convert only (832 blocks).
// ---------------------------------------------------------------------------
__global__ void __launch_bounds__(256) prep_kernel(
    const float* __restrict__ Wq, const float* __restrict__ Wk,
    const float* __restrict__ Wv, const float* __restrict__ Wf,
    __hip_bfloat16* __restrict__ WqB, __hip_bfloat16* __restrict__ WkB,
    __hip_bfloat16* __restrict__ WvB, __hip_bfloat16* __restrict__ WfB) {
  int idx = blockIdx.x * 256 + threadIdx.x;
  if (idx < 8192) WqB[idx] = __float2bfloat16(Wq[idx] * L2E);
  else if (idx < 16384) WkB[idx - 8192] = __float2bfloat16(Wk[idx - 8192]);
  else if (idx < 81920) WvB[idx - 16384] = __float2bfloat16(Wv[idx - 16384]);
  else if (idx < 212992) WfB[idx - 81920] = __float2bfloat16(Wf[idx - 81920]);
}

// ---------------------------------------------------------------------------
// T1: input transposes, merged. z<12: xbT[z] <- x_b[z]; else xfT[z-12] <- x_f.
// ---------------------------------------------------------------------------
__global__ void __launch_bounds__(256) transpose_in_kernel(
    const float* __restrict__ xb, const float* __restrict__ xf,
    __hip_bfloat16* __restrict__ xbT, __hip_bfloat16* __restrict__ xfT) {
  __shared__ float ts[64][65];
  const int z = blockIdx.z;
  const bool isb = (z < 12);
  const int g = isb ? z : z - 12;
  const float* X = (isb ? xb : xf) + (size_t)g * CC * NN;
  __hip_bfloat16* out = (isb ? xbT : xfT) + (size_t)g * NN * CC;
  const int c0 = blockIdx.y * 64, n0 = blockIdx.x * 64;
  const int t = threadIdx.x;
  const float* Xg = X + (size_t)c0 * NN + n0;
  for (int idx = t; idx < 64 * 64; idx += 256) {
    int r = idx >> 6, qq = idx & 63;
    ts[r][qq] = Xg[(size_t)r * NN + qq];
  }
  __syncthreads();
  __hip_bfloat16* og = out + (size_t)n0 * CC + c0;
  for (int idx = t; idx < 64 * 32; idx += 256) {
    int n = idx >> 5, pc = idx & 31;
    ((unsigned*)(og + (size_t)n * CC))[pc] = pack_bf16(ts[2 * pc][n], ts[2 * pc + 1][n]);
  }
}

// ---------------------------------------------------------------------------
// T2: outsT2[b][n][c] = bf16( gamma * (outs_s[b] + outs_s[4+b] + outs_s[8+b]) )
// ---------------------------------------------------------------------------
__global__ void __launch_bounds__(256) transpose_gamma_kernel(
    const float* __restrict__ outs_s, __hip_bfloat16* __restrict__ outsT2,
    const float* __restrict__ gp) {
  __shared__ float ts[64][65];
  const int b = blockIdx.z, c0 = blockIdx.y * 64, n0 = blockIdx.x * 64;
  const int t = threadIdx.x;
  const float sc = gp[0];
  const float* X0 = outs_s + ((size_t)(0 + b) * CC + c0) * NN + n0;
  const float* X1 = outs_s + ((size_t)(4 + b) * CC + c0) * NN + n0;
  const float* X2 = outs_s + ((size_t)(8 + b) * CC + c0) * NN + n0;
  for (int idx = t; idx < 64 * 64; idx += 256) {
    int r = idx >> 6, qq = idx & 63;
    size_t off = (size_t)r * NN + qq;
    ts[r][qq] = X0[off] + X1[off] + X2[off];
  }
  __syncthreads();
  __hip_bfloat16* og = outsT2 + (size_t)b * NN * CC + (size_t)n0 * CC + c0;
  for (int idx = t; idx < 64 * 32; idx += 256) {
    int n = idx >> 5, pc = idx & 31;
    ((unsigned*)(og + (size_t)n * CC))[pc] =
        pack_bf16(ts[2 * pc][n] * sc, ts[2 * pc + 1][n] * sc);
  }
}

// ---------------------------------------------------------------------------
// G1: q/k projection, MFMA.
// ---------------------------------------------------------------------------
__global__ void __launch_bounds__(256) projqk_kernel(
    const __hip_bfloat16* __restrict__ xbT, const __hip_bfloat16* __restrict__ xfT,
    const __hip_bfloat16* __restrict__ WqB, const __hip_bfloat16* __restrict__ WkB,
    const float* __restrict__ bq, const float* __restrict__ bk,
    __hip_bfloat16* __restrict__ qT, __hip_bfloat16* __restrict__ kT) {
  const int gg = blockIdx.y;
  const bool qm = (gg < 12);
  const int g = qm ? gg : gg - 12;
  const __hip_bfloat16* src = (qm ? xbT : xfT) + (size_t)g * NN * CC;
  const __hip_bfloat16* W = qm ? WqB : WkB;
  const float* bias = qm ? bq : bk;
  const float bscale = qm ? L2E : 1.f;
  __hip_bfloat16* dst = (qm ? qT : kT) + (size_t)g * NN * C8;
  const int t = threadIdx.x, w = t >> 6, lane = t & 63;
  const int q = lane >> 4, li = lane & 15;
  const int n_w = blockIdx.x * 256 + w * 64;
  floatx4 acc[2][4];
  floatx4 zf = {0.f, 0.f, 0.f, 0.f};
#pragma unroll
  for (int ot = 0; ot < 2; ++ot)
#pragma unroll
    for (int nt = 0; nt < 4; ++nt) acc[ot][nt] = zf;
#pragma unroll
  for (int kc = 0; kc < 8; ++kc) {
    short8 a[2], bfr[4];
#pragma unroll
    for (int ot = 0; ot < 2; ++ot)
      a[ot] = *(const short8*)(W + (size_t)(ot * 16 + li) * CC + kc * 32 + q * 8);
#pragma unroll
    for (int nt = 0; nt < 4; ++nt)
      bfr[nt] = *(const short8*)(src + (size_t)(n_w + nt * 16 + li) * CC + kc * 32 + q * 8);
#pragma unroll
    for (int ot = 0; ot < 2; ++ot)
#pragma unroll
      for (int nt = 0; nt < 4; ++nt)
        acc[ot][nt] = __builtin_amdgcn_mfma_f32_16x16x32_bf16(a[ot], bfr[nt],
                                                              acc[ot][nt], 0, 0, 0);
  }
#pragma unroll
  for (int ot = 0; ot < 2; ++ot) {
    float bv0 = bias[ot * 16 + q * 4 + 0] * bscale;
    float bv1 = bias[ot * 16 + q * 4 + 1] * bscale;
    float bv2 = bias[ot * 16 + q * 4 + 2] * bscale;
    float bv3 = bias[ot * 16 + q * 4 + 3] * bscale;
#pragma unroll
    for (int nt = 0; nt < 4; ++nt) {
      int n = n_w + nt * 16 + li;
      uint2 pk;
      pk.x = pack_bf16(acc[ot][nt][0] + bv0, acc[ot][nt][1] + bv1);
      pk.y = pack_bf16(acc[ot][nt][2] + bv2, acc[ot][nt][3] + bv3);
      *(uint2*)(dst + (size_t)n * C8 + ot * 16 + q * 4) = pk;
    }
  }
}

// ---------------------------------------------------------------------------
// G2: v projection, MFMA.
// ---------------------------------------------------------------------------
__global__ void __launch_bounds__(256) projv_kernel(
    const __hip_bfloat16* __restrict__ xbT, const __hip_bfloat16* __restrict__ WvB,
    const float* __restrict__ bv, __hip_bfloat16* __restrict__ vB) {
  const int g = blockIdx.y, n0 = blockIdx.x * 64;
  const int t = threadIdx.x, w = t >> 6, lane = t & 63;
  const int q = lane >> 4, li = lane & 15;
  const __hip_bfloat16* src = xbT + (size_t)g * NN * CC;
  __hip_bfloat16* dst = vB + (size_t)g * CC * NN;
  const int o_w = w * 64;
  floatx4 acc[4][4];
  floatx4 zf = {0.f, 0.f, 0.f, 0.f};
#pragma unroll
  for (int ot = 0; ot < 4; ++ot)
#pragma unroll
    for (int nt = 0; nt < 4; ++nt) acc[ot][nt] = zf;
#pragma unroll
  for (int kc = 0; kc < 8; ++kc) {
    short8 a[4], bfr[4];
#pragma unroll
    for (int ot = 0; ot < 4; ++ot)
      a[ot] = *(const short8*)(WvB + (size_t)(o_w + ot * 16 + li) * CC + kc * 32 + q * 8);
#pragma unroll
    for (int nt = 0; nt < 4; ++nt)
      bfr[nt] = *(const short8*)(src + (size_t)(n0 + nt * 16 + li) * CC + kc * 32 + q * 8);
#pragma unroll
    for (int ot = 0; ot < 4; ++ot)
#pragma unroll
      for (int nt = 0; nt < 4; ++nt)
        acc[ot][nt] = __builtin_amdgcn_mfma_f32_16x16x32_bf16(a[ot], bfr[nt],
                                                              acc[ot][nt], 0, 0, 0);
  }
#pragma unroll
  for (int ot = 0; ot < 4; ++ot) {
#pragma unroll
    for (int r = 0; r < 4; ++r) {
      int o = o_w + ot * 16 + q * 4 + r;
      float bo = bv[o];
#pragma unroll
      for (int nt = 0; nt < 4; ++nt)
        dst[(size_t)o * NN + n0 + nt * 16 + li] =
            __float2bfloat16(acc[ot][nt][r] + bo);
    }
  }
}

// ---------------------------------------------------------------------------
// K3: MFMA flash attention. 128-j outer iteration, 4 P-buffers, ONE relaxed
// barrier per 128 j: {s_waitcnt lgkmcnt(0); s_barrier; sched_barrier(0)}
// instead of __syncthreads(), so in-flight global V/K loads are NOT drained
// at the barrier (T4 counted-vmcnt idea: the compiler's dependence-tracked
// vmcnt(N) before first register use is the only wait). The barrier only
// needs LDS ordering (P-tile visibility); vf/kf are register-destined and
// wave-private. Race-freedom: pair(t) rewritten at t+2, after barrier(t+1),
// which all readers of pair(t) passed; reads retire before the reader's own
// lgkmcnt(0) at barrier(t+1).
// ---------------------------------------------------------------------------
__global__ void __launch_bounds__(256) attn_kernel(
    const __hip_bfloat16* __restrict__ qT, const __hip_bfloat16* __restrict__ kT,
    const __hip_bfloat16* __restrict__ vB, float* __restrict__ outs_s) {
  __shared__ uint4 Ps4[4 * 64 * 8];  // 4 x 8KB P buffers, 16B-chunk XOR swizzle
  __shared__ float lsum[64];
  char* Ps0 = (char*)Ps4;
  const int x_ = blockIdx.x;
  const int wk = (x_ & 7) * 96 + (x_ >> 3);  // contiguous range per XCD
  const int g  = wk >> 6;                    // 0..11 (= s*4+b)
  const int i0 = (wk & 63) << 6;
  const int b  = g & 3;
  const int t  = threadIdx.x;
  const int w  = t >> 6;
  const int lane = t & 63, q = lane >> 4, li = lane & 15;

  if (t < 64) lsum[t] = 0.f;

  short8 qf[4];
#pragma unroll
  for (int it = 0; it < 4; ++it)
    qf[it] = *(const short8*)(qT + ((size_t)g * NN + i0 + it * 16 + li) * C8 + q * 8);

  floatx4 acc[4][4];
  floatx4 zf = {0.f, 0.f, 0.f, 0.f};
#pragma unroll
  for (int ct = 0; ct < 4; ++ct)
#pragma unroll
    for (int it = 0; it < 4; ++it) acc[ct][it] = zf;
  float rsum[4] = {0.f, 0.f, 0.f, 0.f};

  const __hip_bfloat16* kb = kT + (size_t)b * NN * C8;
  const __hip_bfloat16* vb = vB + (size_t)g * CC * NN;
  short8 kf0 = *(const short8*)(kb + (size_t)(0 + w * 16 + li) * C8 + q * 8);
  short8 kf1 = *(const short8*)(kb + (size_t)(64 + w * 16 + li) * C8 + q * 8);

  for (int j0 = 0; j0 < NN; j0 += 128) {
    int j0n = (j0 + 128) & (NN - 1);
    char* PsA = Ps0 + ((j0 >> 6) & 2) * 8192;  // pair {0,1} / {2,3} alternates
    char* PsB = PsA + 8192;
    // V frags for subtile A: issue first; with the relaxed barrier these stay
    // in flight across it and land during the S/exp phase.
    short8 vfA[4][2];
#pragma unroll
    for (int ct = 0; ct < 4; ++ct)
#pragma unroll
      for (int kk = 0; kk < 2; ++kk)
        vfA[ct][kk] = *(const short8*)(vb + (size_t)(w * 64 + ct * 16 + li) * NN +
                                       j0 + kk * 32 + q * 8);
    // --- subtile A: S^T strip, exp2, pack, LDS write (stA dies here) ---
    {
      floatx4 stA[4];
#pragma unroll
      for (int it = 0; it < 4; ++it)
        stA[it] = __builtin_amdgcn_mfma_f32_16x16x32_bf16(kf0, qf[it], zf, 0, 0, 0);
      kf0 = *(const short8*)(kb + (size_t)(j0n + w * 16 + li) * C8 + q * 8);
      uint2 pk[4];
#pragma unroll
      for (int it = 0; it < 4; ++it) {
        float e0 = fast_exp2(stA[it][0]), e1 = fast_exp2(stA[it][1]);
        float e2 = fast_exp2(stA[it][2]), e3 = fast_exp2(stA[it][3]);
        rsum[it] += (e0 + e1) + (e2 + e3);
        pk[it].x = pack_bf16(e0, e1);
        pk[it].y = pack_bf16(e2, e3);
      }
#pragma unroll
      for (int it = 0; it < 4; ++it) {
        int row = it * 16 + li;
        int chunk = (w * 2 + (q >> 1)) ^ (row & 7);
        *(uint2*)(PsA + row * 128 + chunk * 16 + (q & 1) * 8) = pk[it];
      }
    }
    // --- subtile B: S^T strip, exp2, pack, LDS write ---
    {
      floatx4 stB[4];
#pragma unroll
      for (int it = 0; it < 4; ++it)
        stB[it] = __builtin_amdgcn_mfma_f32_16x16x32_bf16(kf1, qf[it], zf, 0, 0, 0);
      kf1 = *(const short8*)(kb + (size_t)(j0n + 64 + w * 16 + li) * C8 + q * 8);
      uint2 pk[4];
#pragma unroll
      for (int it = 0; it < 4; ++it) {
        float e0 = fast_exp2(stB[it][0]), e1 = fast_exp2(stB[it][1]);
        float e2 = fast_exp2(stB[it][2]), e3 = fast_exp2(stB[it][3]);
        rsum[it] += (e0 + e1) + (e2 + e3);
        pk[it].x = pack_bf16(e0, e1);
        pk[it].y = pack_bf16(e2, e3);
      }
#pragma unroll
      for (int it = 0; it < 4; ++it) {
        int row = it * 16 + li;
        int chunk = (w * 2 + (q >> 1)) ^ (row & 7);
        *(uint2*)(PsB + row * 128 + chunk * 16 + (q & 1) * 8) = pk[it];
      }
    }
    // Relaxed barrier: LDS-order only, NO vmcnt drain (vf/kf stay in flight).
    asm volatile("s_waitcnt lgkmcnt(0)" ::: "memory");
    __builtin_amdgcn_s_barrier();
    __builtin_amdgcn_sched_barrier(0);
    // --- PV subtile A (vfA dies here) ---
    __builtin_amdgcn_s_setprio(1);
#pragma unroll
    for (int kk = 0; kk < 2; ++kk) {
      short8 pf[4];
#pragma unroll
      for (int it = 0; it < 4; ++it) {
        int row = it * 16 + li;
        int chunk = (kk * 4 + q) ^ (row & 7);
        pf[it] = *(const short8*)(PsA + row * 128 + chunk * 16);
      }
#pragma unroll
      for (int ct = 0; ct < 4; ++ct)
#pragma unroll
        for (int it = 0; it < 4; ++it)
          acc[ct][it] = __builtin_amdgcn_mfma_f32_16x16x32_bf16(
              vfA[ct][kk], pf[it], acc[ct][it], 0, 0, 0);
    }
    __builtin_amdgcn_s_setprio(0);
    // V frags for subtile B (vfA dead -> regs reuse)
    short8 vfB[4][2];
#pragma unroll
    for (int ct = 0; ct < 4; ++ct)
#pragma unroll
      for (int kk = 0; kk < 2; ++kk)
        vfB[ct][kk] = *(const short8*)(vb + (size_t)(w * 64 + ct * 16 + li) * NN +
                                       j0 + 64 + kk * 32 + q * 8);
    // --- PV subtile B ---
    __builtin_amdgcn_s_setprio(1);
#pragma unroll
    for (int kk = 0; kk < 2; ++kk) {
      short8 pf[4];
#pragma unroll
      for (int it = 0; it < 4; ++it) {
        int row = it * 16 + li;
        int chunk = (kk * 4 + q) ^ (row & 7);
        pf[it] = *(const short8*)(PsB + row * 128 + chunk * 16);
      }
#pragma unroll
      for (int ct = 0; ct < 4; ++ct)
#pragma unroll
        for (int it = 0; it < 4; ++it)
          acc[ct][it] = __builtin_amdgcn_mfma_f32_16x16x32_bf16(
              vfB[ct][kk], pf[it], acc[ct][it], 0, 0, 0);
    }
    __builtin_amdgcn_s_setprio(0);
  }
#pragma unroll
  for (int it = 0; it < 4; ++it) {
    float v = rsum[it];
    v += __shfl_xor(v, 16, 64);
    v += __shfl_xor(v, 32, 64);
    if (lane < 16) atomicAdd(&lsum[it * 16 + li], v);
  }
  __syncthreads();
  float inv[4];
#pragma unroll
  for (int it = 0; it < 4; ++it) inv[it] = 1.0f / lsum[it * 16 + li];
  float* ob = outs_s + (size_t)g * CC * NN + i0;
#pragma unroll
  for (int ct = 0; ct < 4; ++ct)
#pragma unroll
    for (int it = 0; it < 4; ++it)
#pragma unroll
      for (int r = 0; r < 4; ++r) {
        int c = w * 64 + ct * 16 + q * 4 + r;
        ob[(size_t)c * NN + it * 16 + li] = acc[ct][it][r] * inv[it];
      }
}

// ---------------------------------------------------------------------------
// G3: final projection, MFMA.
// ---------------------------------------------------------------------------
__global__ void __launch_bounds__(256) final_kernel(
    const __hip_bfloat16* __restrict__ outsT2, const __hip_bfloat16* __restrict__ xfT,
    const __hip_bfloat16* __restrict__ WfB, const float* __restrict__ bfv,
    float* __restrict__ out) {
  const int b = blockIdx.y, n0 = blockIdx.x * 64;
  const int t = threadIdx.x, w = t >> 6, lane = t & 63;
  const int q = lane >> 4, li = lane & 15;
  const int o_w = w * 64;
  const __hip_bfloat16* oT = outsT2 + (size_t)b * NN * CC;
  const __hip_bfloat16* xT = xfT + (size_t)b * NN * CC;
  floatx4 acc[4][4];
  floatx4 zf = {0.f, 0.f, 0.f, 0.f};
#pragma unroll
  for (int ot = 0; ot < 4; ++ot)
#pragma unroll
    for (int nt = 0; nt < 4; ++nt) acc[ot][nt] = zf;
#pragma unroll
  for (int kc = 0; kc < 16; ++kc) {
    const __hip_bfloat16* src = (kc < 8) ? oT : xT;
    int kb = (kc & 7) * 32;
    short8 a[4], bfr[4];
#pragma unroll
    for (int ot = 0; ot < 4; ++ot)
      a[ot] = *(const short8*)(WfB + (size_t)(o_w + ot * 16 + li) * (2 * CC) +
                               kc * 32 + q * 8);
#pragma unroll
    for (int nt = 0; nt < 4; ++nt)
      bfr[nt] = *(const short8*)(src + (size_t)(n0 + nt * 16 + li) * CC + kb + q * 8);
#pragma unroll
    for (int ot = 0; ot < 4; ++ot)
#pragma unroll
      for (int nt = 0; nt < 4; ++nt)
        acc[ot][nt] = __builtin_amdgcn_mfma_f32_16x16x32_bf16(a[ot], bfr[nt],
                                                              acc[ot][nt], 0, 0, 0);
  }
  float* ob = out + (size_t)b * CC * NN;
#pragma unroll
  for (int ot = 0; ot < 4; ++ot)
#pragma unroll
    for (int r = 0; r < 4; ++r) {
      int o = o_w + ot * 16 + q * 4 + r;
      float bo = bfv[o];
#pragma unroll
      for (int nt = 0; nt < 4; ++nt)
        ob[(size_t)o * NN + n0 + nt * 16 + li] = acc[ot][nt][r] + bo;
    }
}

// ---------------------------------------------------------------------------
extern "C" void kernel_launch(void* const* d_in, const int* in_sizes, int n_in,
                              void* d_out, int out_size, void* d_ws,
                              size_t ws_size, hipStream_t stream) {
  const float* x_f = (const float*)d_in[0];
  const float* x_b = (const float*)d_in[1];
  const float* Wq  = (const float*)d_in[2];
  const float* bq  = (const float*)d_in[3];
  const float* Wk  = (const float*)d_in[4];
  const float* bk  = (const float*)d_in[5];
  const float* Wv  = (const float*)d_in[6];
  const float* bv  = (const float*)d_in[7];
  const float* Wf  = (const float*)d_in[8];
  const float* bf  = (const float*)d_in[9];
  const float* gm  = (const float*)d_in[10];
  float* out = (float*)d_out;

  // workspace layout — peak 84.4 MB via aliasing:
  //   [ 0..24) vB       bf16 [12][256][4096]   (projv -> attn)
  //            outsT2   bf16 [4][4096][256]    (tg -> final)  ALIAS: vB dead
  //   [24..32) xfT      bf16 [4][4096][256]    (transpose -> final)
  //   [32..80) outs_s   f32  [12][256][4096]   (attn -> tg)
  //            xbT      bf16 [12][4096][256]   (transpose -> projv) ALIAS
  //   [80..83) qT, [83..84) kT, [84..84.41) weights
  char* ws = (char*)d_ws;
  __hip_bfloat16* vB     = (__hip_bfloat16*)ws;                         // 24 MB
  __hip_bfloat16* outsT2 = (__hip_bfloat16*)ws;                         //  8 MB (alias vB)
  __hip_bfloat16* xfT    = (__hip_bfloat16*)(ws + ((size_t)24 << 20));  //  8 MB
  float*          outs_s = (float*)(ws + ((size_t)32 << 20));           // 48 MB
  __hip_bfloat16* xbT    = (__hip_bfloat16*)(ws + ((size_t)32 << 20));  // 24 MB (alias outs_s)
  __hip_bfloat16* qT     = (__hip_bfloat16*)(ws + ((size_t)80 << 20));  //  3 MB
  __hip_bfloat16* kT     = (__hip_bfloat16*)(ws + ((size_t)83 << 20));  //  1 MB
  __hip_bfloat16* WqB    = (__hip_bfloat16*)(ws + ((size_t)84 << 20));  // 16 KB
  __hip_bfloat16* WkB    = WqB + 8192;                                  // 16 KB
  __hip_bfloat16* WvB    = WkB + 8192;                                  // 128 KB
  __hip_bfloat16* WfB    = WvB + 65536;                                 // 256 KB

  hipLaunchKernelGGL(prep_kernel, dim3(832), dim3(256), 0, stream,
                     Wq, Wk, Wv, Wf, WqB, WkB, WvB, WfB);
  hipLaunchKernelGGL(transpose_in_kernel, dim3(NN / 64, CC / 64, 16),
                     dim3(256), 0, stream, x_b, x_f, xbT, xfT);
  hipLaunchKernelGGL(projqk_kernel, dim3(NN / 256, 16), dim3(256), 0, stream,
                     xbT, xfT, WqB, WkB, bq, bk, qT, kT);
  hipLaunchKernelGGL(projv_kernel, dim3(NN / 64, SS * BB), dim3(256), 0,
                     stream, xbT, WvB, bv, vB);
  hipLaunchKernelGGL(attn_kernel, dim3(768), dim3(256), 0, stream,
                     qT, kT, vB, outs_s);
  hipLaunchKernelGGL(transpose_gamma_kernel, dim3(NN / 64, CC / 64, BB),
                     dim3(256), 0, stream, outs_s, outsT2, gm);
  hipLaunchKernelGGL(final_kernel, dim3(NN / 64, BB), dim3(256), 0, stream,
                     outsT2, xfT, WfB, bf, out);
}